// Round 6
// baseline (197.685 us; speedup 1.0000x reference)
//
#include <hip/hip_runtime.h>
#include <stdint.h>

#define NPTS 8192
#define TILE 2048
#define NTILES (NPTS / TILE)
#define BLK 512             // threads per block (8 waves)
#define WAVES_PER_BLK (BLK / 64)
#define PTS_PER_BLK (WAVES_PER_BLK * 2)      // P=2 queries/wave -> 16
#define BLKS_PER_BATCH (NPTS / PTS_PER_BLK)  // 512 -> grid 1024 = 4 blocks/CU

__device__ __forceinline__ uint32_t umin32(uint32_t a, uint32_t b) { return a < b ? a : b; }
__device__ __forceinline__ uint32_t umax32(uint32_t a, uint32_t b) { return a > b ? a : b; }

// Insert key into sorted top-3 (k0 <= k1 <= k2), unsigned keys. Epilogue only.
__device__ __forceinline__ void ins3(uint32_t key, uint32_t& k0, uint32_t& k1, uint32_t& k2) {
    uint32_t a = umin32(k0, key);
    uint32_t b = umax32(k0, key);
    k0 = a;
    uint32_t c = umin32(k1, b);
    uint32_t d = umax32(k1, b);
    k1 = c;
    k2 = umin32(k2, d);
}

// Merge 4 bin minima -> wave top-3, gather attributes, return this lane's
// weighted contribution for one query point.
__device__ __forceinline__ float point_contrib(
    uint32_t b0, uint32_t b1, uint32_t b2, uint32_t b3,
    int lane, float xp, float yp, float zp,
    const float* __restrict__ xb,
    const float* __restrict__ rot, const float* __restrict__ sc,
    const float* __restrict__ col, const float* __restrict__ opac,
    size_t abase, float inv_nb)
{
    uint32_t K0 = 0xFFFFFFFFu, K1 = 0xFFFFFFFFu, K2 = 0xFFFFFFFFu;
    ins3(b0, K0, K1, K2);
    ins3(b1, K0, K1, K2);
    ins3(b2, K0, K1, K2);
    ins3(b3, K0, K1, K2);
#pragma unroll
    for (int mk = 1; mk < 64; mk <<= 1) {
        uint32_t r0 = (uint32_t)__shfl_xor((int)K0, mk);
        uint32_t r1 = (uint32_t)__shfl_xor((int)K1, mk);
        uint32_t r2 = (uint32_t)__shfl_xor((int)K2, mk);
        ins3(r0, K0, K1, K2);
        ins3(r1, K0, K1, K2);
        ins3(r2, K0, K1, K2);
    }
    int j0 = (int)(K0 & 8191u);
    int j1 = (int)(K1 & 8191u);
    int j2 = (int)(K2 & 8191u);

    // Lane c owns one channel: [0,4)=rot, [4,7)=sc, 7=op, [8,53)=col, 53=dist.
    int c = lane;
    const float* basep = nullptr;
    int stridec = 0, ch = 0;
    float w = 0.0f;
    if (c < 4)       { basep = rot  + abase * 4;  stridec = 4;  ch = c;     w = inv_nb * (1.0f / 4.0f); }
    else if (c < 7)  { basep = sc   + abase * 3;  stridec = 3;  ch = c - 4; w = inv_nb * (1.0f / 3.0f); }
    else if (c == 7) { basep = opac + abase;      stridec = 1;  ch = 0;     w = inv_nb; }
    else if (c < 53) { basep = col  + abase * 45; stridec = 45; ch = c - 8; w = inv_nb * (1.0f / 45.0f); }

    if (basep != nullptr) {
        float v0 = basep[(size_t)j0 * stridec + ch];
        float v1 = basep[(size_t)j1 * stridec + ch];
        float v2 = basep[(size_t)j2 * stridec + ch];
        float mn = (v0 + v1 + v2) * (1.0f / 3.0f);
        float e0 = v0 - mn, e1 = v1 - mn, e2 = v2 - mn;
        // unbiased std over K=3: sqrt(sum(sq) / (K-1))
        return w * sqrtf((e0 * e0 + e1 * e1 + e2 * e2) * 0.5f);
    }
    if (c == 53) {
        // dist_sq.mean over [N, K]: recompute exact distances of the picks
        // (diff-form, unbiased — the inner-loop key bias never reaches output).
        float dx = xb[j0 * 3 + 0] - xp, dy = xb[j0 * 3 + 1] - yp, dz = xb[j0 * 3 + 2] - zp;
        float ds = fmaf(dz, dz, fmaf(dy, dy, dx * dx));
        dx = xb[j1 * 3 + 0] - xp; dy = xb[j1 * 3 + 1] - yp; dz = xb[j1 * 3 + 2] - zp;
        ds += fmaf(dz, dz, fmaf(dy, dy, dx * dx));
        dx = xb[j2 * 3 + 0] - xp; dy = xb[j2 * 3 + 1] - yp; dz = xb[j2 * 3 + 2] - zp;
        ds += fmaf(dz, dz, fmaf(dy, dy, dx * dx));
        return ds * (inv_nb * (1.0f / 3.0f));
    }
    return 0.0f;
}

// min-waves=8 pins VGPR<=64 so 4 blocks/CU = 32 waves/CU can be resident.
// WATCH WRITE_SIZE: if the allocator over-squeezes (R2: ->32 VGPR + spills)
// this shows up as MBs of scratch traffic.
__global__ __launch_bounds__(BLK, 8) void knnreg_kernel(
    const float* __restrict__ xyz,   // [B, N, 3]
    const float* __restrict__ rot,   // [B, N, 4]
    const float* __restrict__ sc,    // [B, N, 3]
    const float* __restrict__ col,   // [B, N, 45]
    const float* __restrict__ opac,  // [B, N, 1]
    float* __restrict__ out,         // [1]
    float inv_nb)                    // 1 / (NPTS * B)
{
    __shared__ __align__(16) float xs[TILE];
    __shared__ __align__(16) float ys[TILE];
    __shared__ __align__(16) float zs[TILE];
    __shared__ float blockAcc;

    const int tid  = threadIdx.x;
    const int lane = tid & 63;
    const int wv   = tid >> 6;
    const int bb   = blockIdx.x / BLKS_PER_BATCH;
    const int blk  = blockIdx.x % BLKS_PER_BATCH;
    const float* xb = xyz + (size_t)bb * NPTS * 3;
    const int ibase = blk * PTS_PER_BLK + wv * 2;

    if (tid == 0) blockAcc = 0.0f;

    // Two query points per wave (broadcast loads).
    const float xq0 = xb[ibase * 3 + 0], yq0 = xb[ibase * 3 + 1], zq0 = xb[ibase * 3 + 2];
    const float xq1 = xb[ibase * 3 + 3], yq1 = xb[ibase * 3 + 4], zq1 = xb[ibase * 3 + 5];

    // Dot-product form: d = (|c|^2 + |q|^2 + eps) - 2 c.q. |c|^2 is RECOMPUTED
    // in-register (3 ops amortized over 2 queries) instead of staged in LDS:
    // cuts LDS traffic 25% (the R6 balance point is LDS~15us vs VALU~15us).
    // eps = 3e-5 keeps the self term positive under chain rounding; ordering
    // unaffected (uniform shift per query). Same fmaf bit-pattern as R5 (abs 0).
    const float q2x0 = -2.0f * xq0, q2y0 = -2.0f * yq0, q2z0 = -2.0f * zq0;
    const float q2x1 = -2.0f * xq1, q2y1 = -2.0f * yq1, q2z1 = -2.0f * zq1;
    const float nqb0 = fmaf(zq0, zq0, fmaf(yq0, yq0, xq0 * xq0)) + 3e-5f;
    const float nqb1 = fmaf(zq1, zq1, fmaf(yq1, yq1, xq1 * xq1)) + 3e-5f;

    // Binned-min selection (see R4): bin=(lane,slot), 1 umin/candidate/query.
    // ALL SCALARS — local arrays fall to scratch (R3: 526 MB spill traffic).
    uint32_t m00 = 0xFFFFFFFFu, m01 = 0xFFFFFFFFu, m02 = 0xFFFFFFFFu, m03 = 0xFFFFFFFFu;
    uint32_t m10 = 0xFFFFFFFFu, m11 = 0xFFFFFFFFu, m12 = 0xFFFFFFFFu, m13 = 0xFFFFFFFFu;

    for (int T = 0; T < NTILES; ++T) {
        __syncthreads();  // protect LDS from previous tile's readers
#pragma unroll
        for (int r = 0; r < TILE / BLK; ++r) {
            int n = r * BLK + tid;
            const float* src = xb + (size_t)(T * TILE + n) * 3;
            xs[n] = src[0];
            ys[n] = src[1];
            zs[n] = src[2];
        }
        __syncthreads();

        const uint32_t jtile = (uint32_t)(T * TILE) + (uint32_t)(lane * 4);
#pragma unroll 2
        for (int it = 0; it < TILE / 256; ++it) {
            const int jl = it * 256 + lane * 4;
            float4 X = *(const float4*)&xs[jl];
            float4 Y = *(const float4*)&ys[jl];
            float4 Z = *(const float4*)&zs[jl];
            const uint32_t jg = jtile + (uint32_t)(it * 256);

#define CAND(cx, cy, cz, u)                                                            \
            do {                                                                       \
                const uint32_t jj = jg + (u);                                          \
                const float cn = fmaf((cz), (cz), fmaf((cy), (cy), (cx) * (cx)));      \
                { float d = fmaf(q2z0, (cz), fmaf(q2y0, (cy), fmaf(q2x0, (cx), cn + nqb0))); \
                  m0##u = umin32(m0##u, (__float_as_uint(d) & 0xFFFFE000u) | jj); }    \
                { float d = fmaf(q2z1, (cz), fmaf(q2y1, (cy), fmaf(q2x1, (cx), cn + nqb1))); \
                  m1##u = umin32(m1##u, (__float_as_uint(d) & 0xFFFFE000u) | jj); }    \
            } while (0)

            CAND(X.x, Y.x, Z.x, 0);
            CAND(X.y, Y.y, Z.y, 1);
            CAND(X.z, Y.z, Z.z, 2);
            CAND(X.w, Y.w, Z.w, 3);
#undef CAND
        }
    }

    const size_t abase = (size_t)bb * NPTS;
    float acc = point_contrib(m00, m01, m02, m03, lane, xq0, yq0, zq0,
                              xb, rot, sc, col, opac, abase, inv_nb);
    acc      += point_contrib(m10, m11, m12, m13, lane, xq1, yq1, zq1,
                              xb, rot, sc, col, opac, abase, inv_nb);

    // Wave reduce, then block reduce, then one global atomic per block.
#pragma unroll
    for (int off = 32; off > 0; off >>= 1) acc += __shfl_xor(acc, off);
    if (lane == 0) atomicAdd(&blockAcc, acc);
    __syncthreads();
    if (tid == 0) atomicAdd(out, blockAcc);
}

extern "C" void kernel_launch(void* const* d_in, const int* in_sizes, int n_in,
                              void* d_out, int out_size, void* d_ws, size_t ws_size,
                              hipStream_t stream) {
    const float* xyz  = (const float*)d_in[0];
    const float* rot  = (const float*)d_in[1];
    const float* sc   = (const float*)d_in[2];
    const float* col  = (const float*)d_in[3];
    const float* opac = (const float*)d_in[4];
    float* out = (float*)d_out;

    const int B = in_sizes[0] / (NPTS * 3);  // = 2
    const float inv_nb = 1.0f / ((float)NPTS * (float)B);

    // d_out is re-poisoned to 0xAA before every launch — zero it ourselves.
    hipMemsetAsync(out, 0, sizeof(float), stream);
    knnreg_kernel<<<dim3(B * BLKS_PER_BATCH), dim3(BLK), 0, stream>>>(
        xyz, rot, sc, col, opac, out, inv_nb);
}

// Round 7
// 107.065 us; speedup vs baseline: 1.8464x; 1.8464x over previous
//
#include <hip/hip_runtime.h>
#include <stdint.h>

#define NPTS 8192
#define TILE 2048
#define NTILES (NPTS / TILE)
#define BLK 256             // threads per block (4 waves) — finer residency packing
#define WAVES_PER_BLK (BLK / 64)
#define PTS_PER_BLK (WAVES_PER_BLK * 2)      // P=2 queries/wave -> 8
#define BLKS_PER_BATCH (NPTS / PTS_PER_BLK)  // 1024 -> grid 2048

__device__ __forceinline__ uint32_t umin32(uint32_t a, uint32_t b) { return a < b ? a : b; }
__device__ __forceinline__ uint32_t umax32(uint32_t a, uint32_t b) { return a > b ? a : b; }

// Insert key into sorted top-3 (k0 <= k1 <= k2), unsigned keys. Epilogue only.
__device__ __forceinline__ void ins3(uint32_t key, uint32_t& k0, uint32_t& k1, uint32_t& k2) {
    uint32_t a = umin32(k0, key);
    uint32_t b = umax32(k0, key);
    k0 = a;
    uint32_t c = umin32(k1, b);
    uint32_t d = umax32(k1, b);
    k1 = c;
    k2 = umin32(k2, d);
}

// Merge 4 bin minima -> wave top-3, gather attributes, return this lane's
// weighted contribution for one query point.
__device__ __forceinline__ float point_contrib(
    uint32_t b0, uint32_t b1, uint32_t b2, uint32_t b3,
    int lane, float xp, float yp, float zp,
    const float* __restrict__ xb,
    const float* __restrict__ rot, const float* __restrict__ sc,
    const float* __restrict__ col, const float* __restrict__ opac,
    size_t abase, float inv_nb)
{
    uint32_t K0 = 0xFFFFFFFFu, K1 = 0xFFFFFFFFu, K2 = 0xFFFFFFFFu;
    ins3(b0, K0, K1, K2);
    ins3(b1, K0, K1, K2);
    ins3(b2, K0, K1, K2);
    ins3(b3, K0, K1, K2);
#pragma unroll
    for (int mk = 1; mk < 64; mk <<= 1) {
        uint32_t r0 = (uint32_t)__shfl_xor((int)K0, mk);
        uint32_t r1 = (uint32_t)__shfl_xor((int)K1, mk);
        uint32_t r2 = (uint32_t)__shfl_xor((int)K2, mk);
        ins3(r0, K0, K1, K2);
        ins3(r1, K0, K1, K2);
        ins3(r2, K0, K1, K2);
    }
    int j0 = (int)(K0 & 8191u);
    int j1 = (int)(K1 & 8191u);
    int j2 = (int)(K2 & 8191u);

    // Lane c owns one channel: [0,4)=rot, [4,7)=sc, 7=op, [8,53)=col, 53=dist.
    int c = lane;
    const float* basep = nullptr;
    int stridec = 0, ch = 0;
    float w = 0.0f;
    if (c < 4)       { basep = rot  + abase * 4;  stridec = 4;  ch = c;     w = inv_nb * (1.0f / 4.0f); }
    else if (c < 7)  { basep = sc   + abase * 3;  stridec = 3;  ch = c - 4; w = inv_nb * (1.0f / 3.0f); }
    else if (c == 7) { basep = opac + abase;      stridec = 1;  ch = 0;     w = inv_nb; }
    else if (c < 53) { basep = col  + abase * 45; stridec = 45; ch = c - 8; w = inv_nb * (1.0f / 45.0f); }

    if (basep != nullptr) {
        float v0 = basep[(size_t)j0 * stridec + ch];
        float v1 = basep[(size_t)j1 * stridec + ch];
        float v2 = basep[(size_t)j2 * stridec + ch];
        float mn = (v0 + v1 + v2) * (1.0f / 3.0f);
        float e0 = v0 - mn, e1 = v1 - mn, e2 = v2 - mn;
        // unbiased std over K=3: sqrt(sum(sq) / (K-1))
        return w * sqrtf((e0 * e0 + e1 * e1 + e2 * e2) * 0.5f);
    }
    if (c == 53) {
        // dist_sq.mean over [N, K]: recompute exact distances of the picks
        // (diff-form, unbiased — the inner-loop key bias never reaches output).
        float dx = xb[j0 * 3 + 0] - xp, dy = xb[j0 * 3 + 1] - yp, dz = xb[j0 * 3 + 2] - zp;
        float ds = fmaf(dz, dz, fmaf(dy, dy, dx * dx));
        dx = xb[j1 * 3 + 0] - xp; dy = xb[j1 * 3 + 1] - yp; dz = xb[j1 * 3 + 2] - zp;
        ds += fmaf(dz, dz, fmaf(dy, dy, dx * dx));
        dx = xb[j2 * 3 + 0] - xp; dy = xb[j2 * 3 + 1] - yp; dz = xb[j2 * 3 + 2] - zp;
        ds += fmaf(dz, dz, fmaf(dy, dy, dx * dx));
        return ds * (inv_nb * (1.0f / 3.0f));
    }
    return 0.0f;
}

// NOTE: min-waves kept LOOSE (4 -> VGPR cap 128). This body does NOT fit in
// 64 VGPRs; any tighter bound makes the allocator overshoot and spill
// (R2: ->32 VGPR/14MB scratch; R6: ->32 VGPR/348MB scratch). Natural ~80 VGPR
// -> 6 waves/SIMD at runtime; LDS 24.6KB/block -> 6 blocks/CU = 24 waves/CU.
__global__ __launch_bounds__(BLK, 4) void knnreg_kernel(
    const float* __restrict__ xyz,   // [B, N, 3]
    const float* __restrict__ rot,   // [B, N, 4]
    const float* __restrict__ sc,    // [B, N, 3]
    const float* __restrict__ col,   // [B, N, 45]
    const float* __restrict__ opac,  // [B, N, 1]
    float* __restrict__ out,         // [1]
    float inv_nb)                    // 1 / (NPTS * B)
{
    __shared__ __align__(16) float xs[TILE];
    __shared__ __align__(16) float ys[TILE];
    __shared__ __align__(16) float zs[TILE];
    __shared__ float blockAcc;

    const int tid  = threadIdx.x;
    const int lane = tid & 63;
    const int wv   = tid >> 6;
    const int bb   = blockIdx.x / BLKS_PER_BATCH;
    const int blk  = blockIdx.x % BLKS_PER_BATCH;
    const float* xb = xyz + (size_t)bb * NPTS * 3;
    const int ibase = blk * PTS_PER_BLK + wv * 2;

    if (tid == 0) blockAcc = 0.0f;

    // Two query points per wave (broadcast loads).
    const float xq0 = xb[ibase * 3 + 0], yq0 = xb[ibase * 3 + 1], zq0 = xb[ibase * 3 + 2];
    const float xq1 = xb[ibase * 3 + 3], yq1 = xb[ibase * 3 + 4], zq1 = xb[ibase * 3 + 5];

    // Dot-product form: d = (|c|^2 + |q|^2 + eps) - 2 c.q. |c|^2 recomputed
    // in-register (3 ops/candidate amortized over 2 queries) — keeps LDS at
    // 3 arrays (LDS-pipe floor ~15us vs 20us with a staged-norm 4th array).
    // eps = 3e-5 keeps the self term positive under chain rounding; ordering
    // unaffected (uniform shift per query). Proven numerics (R5/R6, absmax 0).
    const float q2x0 = -2.0f * xq0, q2y0 = -2.0f * yq0, q2z0 = -2.0f * zq0;
    const float q2x1 = -2.0f * xq1, q2y1 = -2.0f * yq1, q2z1 = -2.0f * zq1;
    const float nqb0 = fmaf(zq0, zq0, fmaf(yq0, yq0, xq0 * xq0)) + 3e-5f;
    const float nqb1 = fmaf(zq1, zq1, fmaf(yq1, yq1, xq1 * xq1)) + 3e-5f;

    // Binned-min selection (see R4): bin=(lane,slot), 1 umin/candidate/query.
    // ALL SCALARS — local arrays fall to scratch (R3: 526 MB spill traffic).
    uint32_t m00 = 0xFFFFFFFFu, m01 = 0xFFFFFFFFu, m02 = 0xFFFFFFFFu, m03 = 0xFFFFFFFFu;
    uint32_t m10 = 0xFFFFFFFFu, m11 = 0xFFFFFFFFu, m12 = 0xFFFFFFFFu, m13 = 0xFFFFFFFFu;

    for (int T = 0; T < NTILES; ++T) {
        __syncthreads();  // protect LDS from previous tile's readers
#pragma unroll
        for (int r = 0; r < TILE / BLK; ++r) {
            int n = r * BLK + tid;
            const float* src = xb + (size_t)(T * TILE + n) * 3;
            xs[n] = src[0];
            ys[n] = src[1];
            zs[n] = src[2];
        }
        __syncthreads();

        const uint32_t jtile = (uint32_t)(T * TILE) + (uint32_t)(lane * 4);
#pragma unroll 2
        for (int it = 0; it < TILE / 256; ++it) {
            const int jl = it * 256 + lane * 4;
            float4 X = *(const float4*)&xs[jl];
            float4 Y = *(const float4*)&ys[jl];
            float4 Z = *(const float4*)&zs[jl];
            const uint32_t jg = jtile + (uint32_t)(it * 256);

#define CAND(cx, cy, cz, u)                                                            \
            do {                                                                       \
                const uint32_t jj = jg + (u);                                          \
                const float cn = fmaf((cz), (cz), fmaf((cy), (cy), (cx) * (cx)));      \
                { float d = fmaf(q2z0, (cz), fmaf(q2y0, (cy), fmaf(q2x0, (cx), cn + nqb0))); \
                  m0##u = umin32(m0##u, (__float_as_uint(d) & 0xFFFFE000u) | jj); }    \
                { float d = fmaf(q2z1, (cz), fmaf(q2y1, (cy), fmaf(q2x1, (cx), cn + nqb1))); \
                  m1##u = umin32(m1##u, (__float_as_uint(d) & 0xFFFFE000u) | jj); }    \
            } while (0)

            CAND(X.x, Y.x, Z.x, 0);
            CAND(X.y, Y.y, Z.y, 1);
            CAND(X.z, Y.z, Z.z, 2);
            CAND(X.w, Y.w, Z.w, 3);
#undef CAND
        }
    }

    const size_t abase = (size_t)bb * NPTS;
    float acc = point_contrib(m00, m01, m02, m03, lane, xq0, yq0, zq0,
                              xb, rot, sc, col, opac, abase, inv_nb);
    acc      += point_contrib(m10, m11, m12, m13, lane, xq1, yq1, zq1,
                              xb, rot, sc, col, opac, abase, inv_nb);

    // Wave reduce, then block reduce, then one global atomic per block.
#pragma unroll
    for (int off = 32; off > 0; off >>= 1) acc += __shfl_xor(acc, off);
    if (lane == 0) atomicAdd(&blockAcc, acc);
    __syncthreads();
    if (tid == 0) atomicAdd(out, blockAcc);
}

extern "C" void kernel_launch(void* const* d_in, const int* in_sizes, int n_in,
                              void* d_out, int out_size, void* d_ws, size_t ws_size,
                              hipStream_t stream) {
    const float* xyz  = (const float*)d_in[0];
    const float* rot  = (const float*)d_in[1];
    const float* sc   = (const float*)d_in[2];
    const float* col  = (const float*)d_in[3];
    const float* opac = (const float*)d_in[4];
    float* out = (float*)d_out;

    const int B = in_sizes[0] / (NPTS * 3);  // = 2
    const float inv_nb = 1.0f / ((float)NPTS * (float)B);

    // d_out is re-poisoned to 0xAA before every launch — zero it ourselves.
    hipMemsetAsync(out, 0, sizeof(float), stream);
    knnreg_kernel<<<dim3(B * BLKS_PER_BATCH), dim3(BLK), 0, stream>>>(
        xyz, rot, sc, col, opac, out, inv_nb);
}

// Round 8
// 93.031 us; speedup vs baseline: 2.1249x; 1.1509x over previous
//
#include <hip/hip_runtime.h>
#include <stdint.h>

#define NPTS 8192
#define CTILE 1024
#define NTILES (NPTS / CTILE)         // 8 staging tiles
#define BLK 512                       // 8 waves
#define QPB 32                        // queries per block (one MFMA row-block)
#define BLKS_PER_BATCH (NPTS / QPB)   // 256

typedef __attribute__((ext_vector_type(8)))  short short8;
typedef __attribute__((ext_vector_type(16))) float float16;

__device__ __forceinline__ uint32_t umin32(uint32_t a, uint32_t b) { return a < b ? a : b; }
__device__ __forceinline__ uint32_t umax32(uint32_t a, uint32_t b) { return a > b ? a : b; }

__device__ __forceinline__ void ins3(uint32_t key, uint32_t& k0, uint32_t& k1, uint32_t& k2) {
    uint32_t a = umin32(k0, key);
    uint32_t b = umax32(k0, key);
    k0 = a;
    uint32_t c = umin32(k1, b);
    uint32_t d = umax32(k1, b);
    k1 = c;
    k2 = umin32(k2, d);
}

// RNE float->bf16 (bits in uint16) and back.
__device__ __forceinline__ uint16_t f2bf(float x) {
    uint32_t u = __float_as_uint(x);
    return (uint16_t)((u + 0x7FFFu + ((u >> 16) & 1u)) >> 16);
}
__device__ __forceinline__ float bf2f(uint16_t s) {
    return __uint_as_float((uint32_t)s << 16);
}

// ---------------- pass 1: pack candidate B-fragments into d_ws --------------
// Per candidate two 16B entries (8 bf16 each), matching the 32x32x16 B layout
// B[k][n]: lane half0 holds k=0..7, half1 k=8..15 of candidate n=lane&31.
//   entry0 (k=0..7):  { c_hi.xyz, c_lo.xyz, 1.0, 1.0 }
//   entry1 (k=8..15): { c_hi.xyz, nc_hi, nc_lo, 0, 0, 0 }
// ws layout per batch: [entry0 for n=0..8191][entry1 for n=0..8191].
__global__ __launch_bounds__(256) void pack_kernel(
    const float* __restrict__ xyz, uint4* __restrict__ ws, int total)
{
    int t = blockIdx.x * 256 + threadIdx.x;
    if (t >= total) return;
    int b = t >> 13;
    int n = t & (NPTS - 1);
    const float* p = xyz + ((size_t)b * NPTS + n) * 3;
    float cx = p[0], cy = p[1], cz = p[2];
    uint16_t bhx = f2bf(cx), bhy = f2bf(cy), bhz = f2bf(cz);
    uint16_t blx = f2bf(cx - bf2f(bhx));
    uint16_t bly = f2bf(cy - bf2f(bhy));
    uint16_t blz = f2bf(cz - bf2f(bhz));
    float nc = fmaf(cz, cz, fmaf(cy, cy, cx * cx));
    uint16_t nch = f2bf(nc), ncl = f2bf(nc - bf2f(nch));
    const uint32_t ONE = 0x3F80u;  // bf16(1.0)
    uint4 a0, a1;
    a0.x = (uint32_t)bhx | ((uint32_t)bhy << 16);
    a0.y = (uint32_t)bhz | ((uint32_t)blx << 16);
    a0.z = (uint32_t)bly | ((uint32_t)blz << 16);
    a0.w = ONE | (ONE << 16);
    a1.x = (uint32_t)bhx | ((uint32_t)bhy << 16);
    a1.y = (uint32_t)bhz | ((uint32_t)nch << 16);
    a1.z = (uint32_t)ncl;
    a1.w = 0u;
    size_t base = (size_t)b * (2 * NPTS);
    ws[base + n]        = a0;
    ws[base + NPTS + n] = a1;
}

// Gather attributes for one query's top-3, return this lane's weighted
// contribution. Lane c owns a channel: [0,4)=rot, [4,7)=sc, 7=op, [8,53)=col,
// 53=dist (exact fp32 recompute — bf16/eps never reach the output values).
__device__ __forceinline__ float point_contrib(
    int j0, int j1, int j2,
    int lane, float xp, float yp, float zp,
    const float* __restrict__ xb,
    const float* __restrict__ rot, const float* __restrict__ sc,
    const float* __restrict__ col, const float* __restrict__ opac,
    size_t abase, float inv_nb)
{
    int c = lane;
    const float* basep = nullptr;
    int stridec = 0, ch = 0;
    float w = 0.0f;
    if (c < 4)       { basep = rot  + abase * 4;  stridec = 4;  ch = c;     w = inv_nb * (1.0f / 4.0f); }
    else if (c < 7)  { basep = sc   + abase * 3;  stridec = 3;  ch = c - 4; w = inv_nb * (1.0f / 3.0f); }
    else if (c == 7) { basep = opac + abase;      stridec = 1;  ch = 0;     w = inv_nb; }
    else if (c < 53) { basep = col  + abase * 45; stridec = 45; ch = c - 8; w = inv_nb * (1.0f / 45.0f); }

    if (basep != nullptr) {
        float v0 = basep[(size_t)j0 * stridec + ch];
        float v1 = basep[(size_t)j1 * stridec + ch];
        float v2 = basep[(size_t)j2 * stridec + ch];
        float mn = (v0 + v1 + v2) * (1.0f / 3.0f);
        float e0 = v0 - mn, e1 = v1 - mn, e2 = v2 - mn;
        return w * sqrtf((e0 * e0 + e1 * e1 + e2 * e2) * 0.5f);  // ddof=1
    }
    if (c == 53) {
        float dx = xb[j0 * 3 + 0] - xp, dy = xb[j0 * 3 + 1] - yp, dz = xb[j0 * 3 + 2] - zp;
        float ds = fmaf(dz, dz, fmaf(dy, dy, dx * dx));
        dx = xb[j1 * 3 + 0] - xp; dy = xb[j1 * 3 + 1] - yp; dz = xb[j1 * 3 + 2] - zp;
        ds += fmaf(dz, dz, fmaf(dy, dy, dx * dx));
        dx = xb[j2 * 3 + 0] - xp; dy = xb[j2 * 3 + 1] - yp; dz = xb[j2 * 3 + 2] - zp;
        ds += fmaf(dz, dz, fmaf(dy, dy, dx * dx));
        return ds * (inv_nb * (1.0f / 3.0f));
    }
    return 0.0f;
}

// ---------------- pass 2: MFMA distance tiles + binned-min top-3 ------------
// d(m,n) = |c|^2 + |q|^2 + eps - 2 q.c via one 32x32x16 bf16 MFMA per tile,
// K-slots: 0-2 (-2q)_h*c_h, 3-5 (-2q)_h*c_l, 6-7 (|q|^2+eps)_{h,l}*1,
// 8-10 (-2q)_l*c_h, 11-12 1*(|c|^2)_{h,l}.  Dropped (-2q)_l*c_l ~ 2^-18 rel.
// NOTE no __launch_bounds__ min-waves (R2/R6: allocator over-squeeze -> spills).
__global__ __launch_bounds__(BLK) void knn_mfma_kernel(
    const float* __restrict__ xyz,
    const float* __restrict__ rot,
    const float* __restrict__ sc,
    const float* __restrict__ colr,
    const float* __restrict__ opac,
    const uint4* __restrict__ pk,
    float* __restrict__ out,
    float inv_nb)
{
    __shared__ __align__(16) uint4 sbuf4[2 * CTILE];   // 32 KB: B tiles, reused as keybuf
    __shared__ int top3j[QPB * 3];
    __shared__ float blockAcc;
    uint32_t* sbufw = (uint32_t*)sbuf4;

    const int tid  = threadIdx.x;
    const int lane = tid & 63;
    const int wv   = tid >> 6;
    const int qcol = lane & 31;     // MFMA col / query-index-within-block
    const int hl   = lane >> 5;     // k-half
    const int bb   = blockIdx.x / BLKS_PER_BATCH;
    const int qbase = (blockIdx.x % BLKS_PER_BATCH) * QPB;
    const float* xb = xyz + (size_t)bb * NPTS * 3;
    const uint4* pkb = pk + (size_t)bb * (2 * NPTS);

    if (tid == 0) blockAcc = 0.0f;

    // --- A fragment (queries; constant across all tiles) ---
    const int qm = qbase + qcol;
    const float qx = xb[qm * 3 + 0], qy = xb[qm * 3 + 1], qz = xb[qm * 3 + 2];
    const float ax = -2.0f * qx, ay = -2.0f * qy, az = -2.0f * qz;
    const uint16_t ahx = f2bf(ax), ahy = f2bf(ay), ahz = f2bf(az);
    const uint16_t alx = f2bf(ax - bf2f(ahx));
    const uint16_t aly = f2bf(ay - bf2f(ahy));
    const uint16_t alz = f2bf(az - bf2f(ahz));
    const float nqe = fmaf(qz, qz, fmaf(qy, qy, qx * qx)) + 1e-3f;  // eps keeps self>0
    const uint16_t nqh = f2bf(nqe), nql = f2bf(nqe - bf2f(nqh));
    short8 A;
    if (hl == 0) {
        A[0] = (short)ahx; A[1] = (short)ahy; A[2] = (short)ahz;
        A[3] = (short)ahx; A[4] = (short)ahy; A[5] = (short)ahz;
        A[6] = (short)nqh; A[7] = (short)nql;
    } else {
        A[0] = (short)alx; A[1] = (short)aly; A[2] = (short)alz;
        A[3] = (short)0x3F80; A[4] = (short)0x3F80;  // 1.0 for the |c|^2 slots
        A[5] = 0; A[6] = 0; A[7] = 0;
    }
    const float16 Z = (float16)0.0f;

    // 16 running min keys — SCALARS ONLY (R3: arrays fall to scratch).
    uint32_t k0 = ~0u, k1 = ~0u, k2 = ~0u, k3 = ~0u, k4 = ~0u, k5 = ~0u, k6 = ~0u, k7 = ~0u;
    uint32_t k8 = ~0u, k9 = ~0u, k10 = ~0u, k11 = ~0u, k12 = ~0u, k13 = ~0u, k14 = ~0u, k15 = ~0u;

    // per-lane LDS byte offset for B-frag reads (t-tile advance via imm offset)
    const int boff = hl * (CTILE * 16) + (wv * 128 + qcol) * 16;

    for (int T = 0; T < NTILES; ++T) {
        __syncthreads();
        // stage 1024 candidates' two entries (contiguous: array0 then array1)
#pragma unroll
        for (int s = 0; s < 4; ++s) {
            int slot = s * BLK + tid;                         // 0..2047
            int n = (slot & (CTILE - 1)) + T * CTILE;
            sbuf4[slot] = pkb[(slot >> 10) * NPTS + n];
        }
        __syncthreads();

        const uint32_t nb0 = (uint32_t)(T * CTILE + wv * 128) + (uint32_t)qcol;
#pragma unroll
        for (int t = 0; t < 4; ++t) {
            short8 Bf = *(const short8*)((const char*)sbuf4 + boff + t * 512);
            float16 D = __builtin_amdgcn_mfma_f32_32x32x16_bf16(A, Bf, Z, 0, 0, 0);
            const uint32_t jj = nb0 + (uint32_t)(t * 32);
#define KU(i, ki) ki = umin32(ki, (__float_as_uint(D[i]) & 0xFFFFE000u) | jj)
            KU(0, k0);  KU(1, k1);  KU(2, k2);  KU(3, k3);
            KU(4, k4);  KU(5, k5);  KU(6, k6);  KU(7, k7);
            KU(8, k8);  KU(9, k9);  KU(10, k10); KU(11, k11);
            KU(12, k12); KU(13, k13); KU(14, k14); KU(15, k15);
#undef KU
        }
    }

    __syncthreads();  // done with sbuf as B tiles — reuse as keybuf[32 rows][256 bins]
    {
        // reg r -> row (r&3) + 8*(r>>2) + 4*hl ; bin col = wv*32 + qcol
        const int base = hl * 1024 + wv * 32 + qcol;   // word index
        sbufw[base +    0] = k0;   sbufw[base +  256] = k1;
        sbufw[base +  512] = k2;   sbufw[base +  768] = k3;
        sbufw[base + 2048] = k4;   sbufw[base + 2304] = k5;
        sbufw[base + 2560] = k6;   sbufw[base + 2816] = k7;
        sbufw[base + 4096] = k8;   sbufw[base + 4352] = k9;
        sbufw[base + 4608] = k10;  sbufw[base + 4864] = k11;
        sbufw[base + 6144] = k12;  sbufw[base + 6400] = k13;
        sbufw[base + 6656] = k14;  sbufw[base + 6912] = k15;
    }
    __syncthreads();

    // merge: wave wv owns rows wv*4+g (g=lane>>4); 16 lanes scan 256 bins.
    {
        const int g = lane >> 4, li = lane & 15;
        const int row = wv * 4 + g;
        uint32_t K0 = ~0u, K1 = ~0u, K2 = ~0u;
#pragma unroll
        for (int s = 0; s < 16; ++s) ins3(sbufw[row * 256 + li + s * 16], K0, K1, K2);
#pragma unroll
        for (int mk = 1; mk < 16; mk <<= 1) {
            uint32_t r0 = (uint32_t)__shfl_xor((int)K0, mk);
            uint32_t r1 = (uint32_t)__shfl_xor((int)K1, mk);
            uint32_t r2 = (uint32_t)__shfl_xor((int)K2, mk);
            ins3(r0, K0, K1, K2);
            ins3(r1, K0, K1, K2);
            ins3(r2, K0, K1, K2);
        }
        if (li == 0) {
            top3j[row * 3 + 0] = (int)(K0 & 8191u);
            top3j[row * 3 + 1] = (int)(K1 & 8191u);
            top3j[row * 3 + 2] = (int)(K2 & 8191u);
        }
    }
    __syncthreads();

    // gather: wave wv handles queries wv*4 .. wv*4+3
    float acc = 0.0f;
    const size_t abase = (size_t)bb * NPTS;
    for (int i = 0; i < 4; ++i) {
        const int q = wv * 4 + i;
        const int j0 = top3j[q * 3 + 0];
        const int j1 = top3j[q * 3 + 1];
        const int j2 = top3j[q * 3 + 2];
        const int qi = qbase + q;
        const float xp = xb[qi * 3 + 0], yp = xb[qi * 3 + 1], zp = xb[qi * 3 + 2];
        acc += point_contrib(j0, j1, j2, lane, xp, yp, zp,
                             xb, rot, sc, colr, opac, abase, inv_nb);
    }

#pragma unroll
    for (int off = 32; off > 0; off >>= 1) acc += __shfl_xor(acc, off);
    if (lane == 0) atomicAdd(&blockAcc, acc);
    __syncthreads();
    if (tid == 0) atomicAdd(out, blockAcc);
}

extern "C" void kernel_launch(void* const* d_in, const int* in_sizes, int n_in,
                              void* d_out, int out_size, void* d_ws, size_t ws_size,
                              hipStream_t stream) {
    const float* xyz  = (const float*)d_in[0];
    const float* rot  = (const float*)d_in[1];
    const float* sc   = (const float*)d_in[2];
    const float* colr = (const float*)d_in[3];
    const float* opac = (const float*)d_in[4];
    float* out = (float*)d_out;

    const int B = in_sizes[0] / (NPTS * 3);  // = 2
    const float inv_nb = 1.0f / ((float)NPTS * (float)B);
    const int total = B * NPTS;

    // d_out / d_ws re-poisoned to 0xAA each launch: zero out; repack ws fully.
    hipMemsetAsync(out, 0, sizeof(float), stream);
    pack_kernel<<<dim3((total + 255) / 256), dim3(256), 0, stream>>>(
        xyz, (uint4*)d_ws, total);
    knn_mfma_kernel<<<dim3(B * BLKS_PER_BATCH), dim3(BLK), 0, stream>>>(
        xyz, rot, sc, colr, opac, (const uint4*)d_ws, out, inv_nb);
}

// Round 9
// 87.240 us; speedup vs baseline: 2.2660x; 1.0664x over previous
//
#include <hip/hip_runtime.h>
#include <stdint.h>

#define NPTS 8192
#define CTILE 2048
#define NTILES (NPTS / CTILE)         // 4 staging tiles
#define BLK 512                       // 8 waves
#define QPB 32                        // queries per block (one MFMA row-block)
#define BLKS_PER_BATCH (NPTS / QPB)   // 256

typedef __attribute__((ext_vector_type(8)))  short short8;
typedef __attribute__((ext_vector_type(16))) float float16;

__device__ __forceinline__ uint32_t umin32(uint32_t a, uint32_t b) { return a < b ? a : b; }
__device__ __forceinline__ uint32_t umax32(uint32_t a, uint32_t b) { return a > b ? a : b; }

__device__ __forceinline__ void ins3(uint32_t key, uint32_t& k0, uint32_t& k1, uint32_t& k2) {
    uint32_t a = umin32(k0, key);
    uint32_t b = umax32(k0, key);
    k0 = a;
    uint32_t c = umin32(k1, b);
    uint32_t d = umax32(k1, b);
    k1 = c;
    k2 = umin32(k2, d);
}

// RNE float->bf16 (bits in uint16) and back.
__device__ __forceinline__ uint16_t f2bf(float x) {
    uint32_t u = __float_as_uint(x);
    return (uint16_t)((u + 0x7FFFu + ((u >> 16) & 1u)) >> 16);
}
__device__ __forceinline__ float bf2f(uint16_t s) {
    return __uint_as_float((uint32_t)s << 16);
}

// Gather attributes for one query's top-3; lane c owns a channel:
// [0,4)=rot, [4,7)=sc, 7=op, [8,53)=col, 53=dist (exact fp32 recompute —
// bf16/eps approximations never reach the output values).
__device__ __forceinline__ float point_contrib(
    int j0, int j1, int j2,
    int lane, float xp, float yp, float zp,
    const float* __restrict__ xb,
    const float* __restrict__ rot, const float* __restrict__ sc,
    const float* __restrict__ col, const float* __restrict__ opac,
    size_t abase, float inv_nb)
{
    int c = lane;
    const float* basep = nullptr;
    int stridec = 0, ch = 0;
    float w = 0.0f;
    if (c < 4)       { basep = rot  + abase * 4;  stridec = 4;  ch = c;     w = inv_nb * (1.0f / 4.0f); }
    else if (c < 7)  { basep = sc   + abase * 3;  stridec = 3;  ch = c - 4; w = inv_nb * (1.0f / 3.0f); }
    else if (c == 7) { basep = opac + abase;      stridec = 1;  ch = 0;     w = inv_nb; }
    else if (c < 53) { basep = col  + abase * 45; stridec = 45; ch = c - 8; w = inv_nb * (1.0f / 45.0f); }

    if (basep != nullptr) {
        float v0 = basep[(size_t)j0 * stridec + ch];
        float v1 = basep[(size_t)j1 * stridec + ch];
        float v2 = basep[(size_t)j2 * stridec + ch];
        float mn = (v0 + v1 + v2) * (1.0f / 3.0f);
        float e0 = v0 - mn, e1 = v1 - mn, e2 = v2 - mn;
        return w * sqrtf((e0 * e0 + e1 * e1 + e2 * e2) * 0.5f);  // ddof=1
    }
    if (c == 53) {
        float dx = xb[j0 * 3 + 0] - xp, dy = xb[j0 * 3 + 1] - yp, dz = xb[j0 * 3 + 2] - zp;
        float ds = fmaf(dz, dz, fmaf(dy, dy, dx * dx));
        dx = xb[j1 * 3 + 0] - xp; dy = xb[j1 * 3 + 1] - yp; dz = xb[j1 * 3 + 2] - zp;
        ds += fmaf(dz, dz, fmaf(dy, dy, dx * dx));
        dx = xb[j2 * 3 + 0] - xp; dy = xb[j2 * 3 + 1] - yp; dz = xb[j2 * 3 + 2] - zp;
        ds += fmaf(dz, dz, fmaf(dy, dy, dx * dx));
        return ds * (inv_nb * (1.0f / 3.0f));
    }
    return 0.0f;
}

// d(m,n) = |c|^2 + |q|^2 + eps - 2 q.c via one 32x32x16 bf16 MFMA per tile.
// K-slots: 0-2 (-2q)_h*c_h, 3-5 (-2q)_h*c_l, 6-7 (|q|^2+eps)_{h,l}*1,
// 8-10 (-2q)_l*c_h, 11-12 1*(|c|^2)_{h,l}. Dropped (-2q)_l*c_l ~ 2^-18 rel.
// B-fragments are built IN the staging loop (pack kernel folded — saves a
// launch + ws round-trip). No __launch_bounds__ min-waves (R2/R6: allocator
// over-squeeze -> spills). LDS 64 KB -> 2 blocks/CU.
__global__ __launch_bounds__(BLK) void knn_mfma_kernel(
    const float* __restrict__ xyz,
    const float* __restrict__ rot,
    const float* __restrict__ sc,
    const float* __restrict__ colr,
    const float* __restrict__ opac,
    float* __restrict__ out,
    float inv_nb)
{
    __shared__ __align__(16) uint4 sbuf4[2 * CTILE];   // 64 KB: B tiles, reused as keybuf
    __shared__ int top3j[QPB * 3];
    __shared__ float blockAcc;
    uint32_t* sbufw = (uint32_t*)sbuf4;

    const int tid  = threadIdx.x;
    const int lane = tid & 63;
    const int wv   = tid >> 6;
    const int qcol = lane & 31;     // MFMA col (candidate within 32-tile)
    const int hl   = lane >> 5;     // k-half
    const int bb   = blockIdx.x / BLKS_PER_BATCH;
    const int qbase = (blockIdx.x % BLKS_PER_BATCH) * QPB;
    const float* xb = xyz + (size_t)bb * NPTS * 3;

    if (tid == 0) blockAcc = 0.0f;

    // --- A fragment (queries; constant across all tiles) — layout validated R8 ---
    const int qm = qbase + qcol;
    const float qx = xb[qm * 3 + 0], qy = xb[qm * 3 + 1], qz = xb[qm * 3 + 2];
    const float ax = -2.0f * qx, ay = -2.0f * qy, az = -2.0f * qz;
    const uint16_t ahx = f2bf(ax), ahy = f2bf(ay), ahz = f2bf(az);
    const uint16_t alx = f2bf(ax - bf2f(ahx));
    const uint16_t aly = f2bf(ay - bf2f(ahy));
    const uint16_t alz = f2bf(az - bf2f(ahz));
    const float nqe = fmaf(qz, qz, fmaf(qy, qy, qx * qx)) + 1e-3f;  // eps keeps self>0
    const uint16_t nqh = f2bf(nqe), nql = f2bf(nqe - bf2f(nqh));
    short8 A;
    if (hl == 0) {
        A[0] = (short)ahx; A[1] = (short)ahy; A[2] = (short)ahz;
        A[3] = (short)ahx; A[4] = (short)ahy; A[5] = (short)ahz;
        A[6] = (short)nqh; A[7] = (short)nql;
    } else {
        A[0] = (short)alx; A[1] = (short)aly; A[2] = (short)alz;
        A[3] = (short)0x3F80; A[4] = (short)0x3F80;  // 1.0 for the |c|^2 slots
        A[5] = 0; A[6] = 0; A[7] = 0;
    }
    const float16 Z = (float16)0.0f;

    // 16 running min keys — SCALARS ONLY (R3: arrays fall to scratch).
    uint32_t k0 = ~0u, k1 = ~0u, k2 = ~0u, k3 = ~0u, k4 = ~0u, k5 = ~0u, k6 = ~0u, k7 = ~0u;
    uint32_t k8 = ~0u, k9 = ~0u, k10 = ~0u, k11 = ~0u, k12 = ~0u, k13 = ~0u, k14 = ~0u, k15 = ~0u;

    // per-lane LDS byte offset for B-frag reads (t advances via imm offset)
    const int boff = (hl * CTILE + wv * 256 + qcol) * 16;

    for (int T = 0; T < NTILES; ++T) {
        __syncthreads();
        // Stage 2048 candidates: build both B-frag entries in registers.
        //   entry0 (k=0..7):  { c_hi.xyz, c_lo.xyz, 1.0, 1.0 }
        //   entry1 (k=8..15): { c_hi.xyz, nc_hi, nc_lo, 0, 0, 0 }
#pragma unroll
        for (int s = 0; s < CTILE / BLK; ++s) {
            int nl = s * BLK + tid;
            const float* p = xb + (size_t)(T * CTILE + nl) * 3;
            float cx = p[0], cy = p[1], cz = p[2];
            uint16_t bhx = f2bf(cx), bhy = f2bf(cy), bhz = f2bf(cz);
            uint16_t blx = f2bf(cx - bf2f(bhx));
            uint16_t bly = f2bf(cy - bf2f(bhy));
            uint16_t blz = f2bf(cz - bf2f(bhz));
            float nc = fmaf(cz, cz, fmaf(cy, cy, cx * cx));
            uint16_t nch = f2bf(nc), ncl = f2bf(nc - bf2f(nch));
            uint4 a0, a1;
            a0.x = (uint32_t)bhx | ((uint32_t)bhy << 16);
            a0.y = (uint32_t)bhz | ((uint32_t)blx << 16);
            a0.z = (uint32_t)bly | ((uint32_t)blz << 16);
            a0.w = 0x3F80u | (0x3F80u << 16);
            a1.x = (uint32_t)bhx | ((uint32_t)bhy << 16);
            a1.y = (uint32_t)bhz | ((uint32_t)nch << 16);
            a1.z = (uint32_t)ncl;
            a1.w = 0u;
            sbuf4[nl]         = a0;
            sbuf4[CTILE + nl] = a1;
        }
        __syncthreads();

        const uint32_t nb0 = (uint32_t)(T * CTILE + wv * 256) + (uint32_t)qcol;
#pragma unroll 2
        for (int t = 0; t < 8; ++t) {
            short8 Bf = *(const short8*)((const char*)sbuf4 + boff + t * 512);
            float16 D = __builtin_amdgcn_mfma_f32_32x32x16_bf16(A, Bf, Z, 0, 0, 0);
            const uint32_t jj = nb0 + (uint32_t)(t * 32);
#define KU(i, ki) ki = umin32(ki, (__float_as_uint(D[i]) & 0xFFFFE000u) | jj)
            KU(0, k0);  KU(1, k1);  KU(2, k2);  KU(3, k3);
            KU(4, k4);  KU(5, k5);  KU(6, k6);  KU(7, k7);
            KU(8, k8);  KU(9, k9);  KU(10, k10); KU(11, k11);
            KU(12, k12); KU(13, k13); KU(14, k14); KU(15, k15);
#undef KU
        }
    }

    __syncthreads();  // done with sbuf as B tiles — reuse as keybuf[32 rows][256 bins]
    {
        // reg r -> row (r&3) + 8*(r>>2) + 4*hl ; bin col = wv*32 + qcol  (R8-validated)
        const int base = hl * 1024 + wv * 32 + qcol;   // word index
        sbufw[base +    0] = k0;   sbufw[base +  256] = k1;
        sbufw[base +  512] = k2;   sbufw[base +  768] = k3;
        sbufw[base + 2048] = k4;   sbufw[base + 2304] = k5;
        sbufw[base + 2560] = k6;   sbufw[base + 2816] = k7;
        sbufw[base + 4096] = k8;   sbufw[base + 4352] = k9;
        sbufw[base + 4608] = k10;  sbufw[base + 4864] = k11;
        sbufw[base + 6144] = k12;  sbufw[base + 6400] = k13;
        sbufw[base + 6656] = k14;  sbufw[base + 6912] = k15;
    }
    __syncthreads();

    // merge: wave wv owns rows wv*4+g (g=lane>>4); 16 lanes scan 256 bins.
    {
        const int g = lane >> 4, li = lane & 15;
        const int row = wv * 4 + g;
        uint32_t K0 = ~0u, K1 = ~0u, K2 = ~0u;
#pragma unroll
        for (int s = 0; s < 16; ++s) ins3(sbufw[row * 256 + li + s * 16], K0, K1, K2);
#pragma unroll
        for (int mk = 1; mk < 16; mk <<= 1) {
            uint32_t r0 = (uint32_t)__shfl_xor((int)K0, mk);
            uint32_t r1 = (uint32_t)__shfl_xor((int)K1, mk);
            uint32_t r2 = (uint32_t)__shfl_xor((int)K2, mk);
            ins3(r0, K0, K1, K2);
            ins3(r1, K0, K1, K2);
            ins3(r2, K0, K1, K2);
        }
        if (li == 0) {
            top3j[row * 3 + 0] = (int)(K0 & 8191u);
            top3j[row * 3 + 1] = (int)(K1 & 8191u);
            top3j[row * 3 + 2] = (int)(K2 & 8191u);
        }
    }
    __syncthreads();

    // gather: wave wv handles queries wv*4 .. wv*4+3
    float acc = 0.0f;
    const size_t abase = (size_t)bb * NPTS;
    for (int i = 0; i < 4; ++i) {
        const int q = wv * 4 + i;
        const int j0 = top3j[q * 3 + 0];
        const int j1 = top3j[q * 3 + 1];
        const int j2 = top3j[q * 3 + 2];
        const int qi = qbase + q;
        const float xp = xb[qi * 3 + 0], yp = xb[qi * 3 + 1], zp = xb[qi * 3 + 2];
        acc += point_contrib(j0, j1, j2, lane, xp, yp, zp,
                             xb, rot, sc, colr, opac, abase, inv_nb);
    }

#pragma unroll
    for (int off = 32; off > 0; off >>= 1) acc += __shfl_xor(acc, off);
    if (lane == 0) atomicAdd(&blockAcc, acc);
    __syncthreads();
    if (tid == 0) atomicAdd(out, blockAcc);
}

extern "C" void kernel_launch(void* const* d_in, const int* in_sizes, int n_in,
                              void* d_out, int out_size, void* d_ws, size_t ws_size,
                              hipStream_t stream) {
    const float* xyz  = (const float*)d_in[0];
    const float* rot  = (const float*)d_in[1];
    const float* sc   = (const float*)d_in[2];
    const float* colr = (const float*)d_in[3];
    const float* opac = (const float*)d_in[4];
    float* out = (float*)d_out;

    const int B = in_sizes[0] / (NPTS * 3);  // = 2
    const float inv_nb = 1.0f / ((float)NPTS * (float)B);

    // d_out re-poisoned to 0xAA each launch — zero it ourselves.
    hipMemsetAsync(out, 0, sizeof(float), stream);
    knn_mfma_kernel<<<dim3(B * BLKS_PER_BATCH), dim3(BLK), 0, stream>>>(
        xyz, rot, sc, colr, opac, out, inv_nb);
}

// Round 10
// 85.092 us; speedup vs baseline: 2.3232x; 1.0252x over previous
//
#include <hip/hip_runtime.h>
#include <stdint.h>

#define NPTS 8192
#define BLK 512                       // 8 waves
#define QPB 32                        // queries per block (one MFMA row-block)
#define BLKS_PER_BATCH (NPTS / QPB)   // 256 -> grid 512 (2 blocks/CU)

typedef __attribute__((ext_vector_type(8)))  short short8;
typedef __attribute__((ext_vector_type(16))) float float16;

__device__ __forceinline__ uint32_t umin32(uint32_t a, uint32_t b) { return a < b ? a : b; }
__device__ __forceinline__ uint32_t umax32(uint32_t a, uint32_t b) { return a > b ? a : b; }

__device__ __forceinline__ void ins3(uint32_t key, uint32_t& k0, uint32_t& k1, uint32_t& k2) {
    uint32_t a = umin32(k0, key);
    uint32_t b = umax32(k0, key);
    k0 = a;
    uint32_t c = umin32(k1, b);
    uint32_t d = umax32(k1, b);
    k1 = c;
    k2 = umin32(k2, d);
}

// RNE float->bf16 (bits in uint16) and back.
__device__ __forceinline__ uint16_t f2bf(float x) {
    uint32_t u = __float_as_uint(x);
    return (uint16_t)((u + 0x7FFFu + ((u >> 16) & 1u)) >> 16);
}
__device__ __forceinline__ float bf2f(uint16_t s) {
    return __uint_as_float((uint32_t)s << 16);
}

// ---------------- pass 1: pack candidate B-fragments into d_ws --------------
// Per candidate two 16B entries (8 bf16 each), 32x32x16 B layout (R8-validated):
//   entry0 (k=0..7):  { c_hi.xyz, c_lo.xyz, 1.0, 1.0 }
//   entry1 (k=8..15): { c_hi.xyz, nc_hi, nc_lo, 0, 0, 0 }
// ws per batch: [entry0 n=0..8191][entry1 n=0..8191].  Also zeroes d_out
// (folds the memset dispatch; stream order guarantees it precedes pass 2).
__global__ __launch_bounds__(256) void pack_kernel(
    const float* __restrict__ xyz, uint4* __restrict__ ws,
    float* __restrict__ out, int total)
{
    int t = blockIdx.x * 256 + threadIdx.x;
    if (t == 0) *out = 0.0f;
    if (t >= total) return;
    int b = t >> 13;
    int n = t & (NPTS - 1);
    const float* p = xyz + ((size_t)b * NPTS + n) * 3;
    float cx = p[0], cy = p[1], cz = p[2];
    uint16_t bhx = f2bf(cx), bhy = f2bf(cy), bhz = f2bf(cz);
    uint16_t blx = f2bf(cx - bf2f(bhx));
    uint16_t bly = f2bf(cy - bf2f(bhy));
    uint16_t blz = f2bf(cz - bf2f(bhz));
    float nc = fmaf(cz, cz, fmaf(cy, cy, cx * cx));
    uint16_t nch = f2bf(nc), ncl = f2bf(nc - bf2f(nch));
    const uint32_t ONE = 0x3F80u;  // bf16(1.0)
    uint4 a0, a1;
    a0.x = (uint32_t)bhx | ((uint32_t)bhy << 16);
    a0.y = (uint32_t)bhz | ((uint32_t)blx << 16);
    a0.z = (uint32_t)bly | ((uint32_t)blz << 16);
    a0.w = ONE | (ONE << 16);
    a1.x = (uint32_t)bhx | ((uint32_t)bhy << 16);
    a1.y = (uint32_t)bhz | ((uint32_t)nch << 16);
    a1.z = (uint32_t)ncl;
    a1.w = 0u;
    size_t base = (size_t)b * (2 * NPTS);
    ws[base + n]        = a0;
    ws[base + NPTS + n] = a1;
}

// Gather attributes for one query's top-3; lane c owns a channel:
// [0,4)=rot, [4,7)=sc, 7=op, [8,53)=col, 53=dist (exact fp32 recompute —
// bf16/eps approximations never reach the output values).
__device__ __forceinline__ float point_contrib(
    int j0, int j1, int j2,
    int lane, float xp, float yp, float zp,
    const float* __restrict__ xb,
    const float* __restrict__ rot, const float* __restrict__ sc,
    const float* __restrict__ col, const float* __restrict__ opac,
    size_t abase, float inv_nb)
{
    int c = lane;
    const float* basep = nullptr;
    int stridec = 0, ch = 0;
    float w = 0.0f;
    if (c < 4)       { basep = rot  + abase * 4;  stridec = 4;  ch = c;     w = inv_nb * (1.0f / 4.0f); }
    else if (c < 7)  { basep = sc   + abase * 3;  stridec = 3;  ch = c - 4; w = inv_nb * (1.0f / 3.0f); }
    else if (c == 7) { basep = opac + abase;      stridec = 1;  ch = 0;     w = inv_nb; }
    else if (c < 53) { basep = col  + abase * 45; stridec = 45; ch = c - 8; w = inv_nb * (1.0f / 45.0f); }

    if (basep != nullptr) {
        float v0 = basep[(size_t)j0 * stridec + ch];
        float v1 = basep[(size_t)j1 * stridec + ch];
        float v2 = basep[(size_t)j2 * stridec + ch];
        float mn = (v0 + v1 + v2) * (1.0f / 3.0f);
        float e0 = v0 - mn, e1 = v1 - mn, e2 = v2 - mn;
        return w * sqrtf((e0 * e0 + e1 * e1 + e2 * e2) * 0.5f);  // ddof=1
    }
    if (c == 53) {
        float dx = xb[j0 * 3 + 0] - xp, dy = xb[j0 * 3 + 1] - yp, dz = xb[j0 * 3 + 2] - zp;
        float ds = fmaf(dz, dz, fmaf(dy, dy, dx * dx));
        dx = xb[j1 * 3 + 0] - xp; dy = xb[j1 * 3 + 1] - yp; dz = xb[j1 * 3 + 2] - zp;
        ds += fmaf(dz, dz, fmaf(dy, dy, dx * dx));
        dx = xb[j2 * 3 + 0] - xp; dy = xb[j2 * 3 + 1] - yp; dz = xb[j2 * 3 + 2] - zp;
        ds += fmaf(dz, dz, fmaf(dy, dy, dx * dx));
        return ds * (inv_nb * (1.0f / 3.0f));
    }
    return 0.0f;
}

// ---------------- pass 2: barrier-free MFMA K-loop ------------------------
// d(m,n) = |c|^2+|q|^2+eps-2q.c via one 32x32x16 bf16 MFMA per 32 candidates.
// B-fragments read DIRECTLY from global (L2-resident 512 KB/batch) — no LDS
// staging, no __syncthreads in the K-loop. Wave wv scans candidates
// [wv*1024, wv*1024+1024); bins are (wave,qcol) columns of the keybuf.
// No __launch_bounds__ min-waves (R2/R6: allocator over-squeeze -> spills).
__global__ __launch_bounds__(BLK) void knn_mfma_kernel(
    const float* __restrict__ xyz,
    const float* __restrict__ rot,
    const float* __restrict__ sc,
    const float* __restrict__ colr,
    const float* __restrict__ opac,
    const uint4* __restrict__ pk,
    float* __restrict__ out,
    float inv_nb)
{
    __shared__ uint32_t keybuf[QPB * 256];   // 32 KB
    __shared__ int top3j[QPB * 3];
    __shared__ float blockAcc;

    const int tid  = threadIdx.x;
    const int lane = tid & 63;
    const int wv   = tid >> 6;
    const int qcol = lane & 31;     // MFMA col (candidate within 32-tile)
    const int hl   = lane >> 5;     // k-half
    const int bb   = blockIdx.x / BLKS_PER_BATCH;
    const int qbase = (blockIdx.x % BLKS_PER_BATCH) * QPB;
    const float* xb = xyz + (size_t)bb * NPTS * 3;
    const uint4* pkb = pk + (size_t)bb * (2 * NPTS);

    if (tid == 0) blockAcc = 0.0f;

    // --- A fragment (queries; constant across all tiles) — R8/R9-validated ---
    const int qm = qbase + qcol;
    const float qx = xb[qm * 3 + 0], qy = xb[qm * 3 + 1], qz = xb[qm * 3 + 2];
    const float ax = -2.0f * qx, ay = -2.0f * qy, az = -2.0f * qz;
    const uint16_t ahx = f2bf(ax), ahy = f2bf(ay), ahz = f2bf(az);
    const uint16_t alx = f2bf(ax - bf2f(ahx));
    const uint16_t aly = f2bf(ay - bf2f(ahy));
    const uint16_t alz = f2bf(az - bf2f(ahz));
    const float nqe = fmaf(qz, qz, fmaf(qy, qy, qx * qx)) + 1e-3f;  // eps keeps self>0
    const uint16_t nqh = f2bf(nqe), nql = f2bf(nqe - bf2f(nqh));
    short8 A;
    if (hl == 0) {
        A[0] = (short)ahx; A[1] = (short)ahy; A[2] = (short)ahz;
        A[3] = (short)ahx; A[4] = (short)ahy; A[5] = (short)ahz;
        A[6] = (short)nqh; A[7] = (short)nql;
    } else {
        A[0] = (short)alx; A[1] = (short)aly; A[2] = (short)alz;
        A[3] = (short)0x3F80; A[4] = (short)0x3F80;  // 1.0 for the |c|^2 slots
        A[5] = 0; A[6] = 0; A[7] = 0;
    }
    const float16 Z = (float16)0.0f;

    // 16 running min keys — SCALARS ONLY (R3: arrays fall to scratch).
    uint32_t k0 = ~0u, k1 = ~0u, k2 = ~0u, k3 = ~0u, k4 = ~0u, k5 = ~0u, k6 = ~0u, k7 = ~0u;
    uint32_t k8 = ~0u, k9 = ~0u, k10 = ~0u, k11 = ~0u, k12 = ~0u, k13 = ~0u, k14 = ~0u, k15 = ~0u;

    // Barrier-free K-loop: lane's B-frag pointer; 32 independent iterations.
    const int nstart = wv * 1024;
    const uint4* lanep = pkb + (size_t)hl * NPTS + nstart + qcol;
    const uint32_t nb0 = (uint32_t)(nstart + qcol);
#pragma unroll 4
    for (int t = 0; t < 32; ++t) {
        uint4 wrd = lanep[t * 32];
        short8 Bf;
        Bf[0] = (short)(wrd.x & 0xFFFFu); Bf[1] = (short)(wrd.x >> 16);
        Bf[2] = (short)(wrd.y & 0xFFFFu); Bf[3] = (short)(wrd.y >> 16);
        Bf[4] = (short)(wrd.z & 0xFFFFu); Bf[5] = (short)(wrd.z >> 16);
        Bf[6] = (short)(wrd.w & 0xFFFFu); Bf[7] = (short)(wrd.w >> 16);
        float16 D = __builtin_amdgcn_mfma_f32_32x32x16_bf16(A, Bf, Z, 0, 0, 0);
        const uint32_t jj = nb0 + (uint32_t)(t * 32);
#define KU(i, ki) ki = umin32(ki, (__float_as_uint(D[i]) & 0xFFFFE000u) | jj)
        KU(0, k0);  KU(1, k1);  KU(2, k2);  KU(3, k3);
        KU(4, k4);  KU(5, k5);  KU(6, k6);  KU(7, k7);
        KU(8, k8);  KU(9, k9);  KU(10, k10); KU(11, k11);
        KU(12, k12); KU(13, k13); KU(14, k14); KU(15, k15);
#undef KU
    }

    // keybuf[row][256 bins]: reg r -> row (r&3)+8*(r>>2)+4*hl; col wv*32+qcol.
    {
        const int base = hl * 1024 + wv * 32 + qcol;   // word index (4 rows * 256)
        keybuf[base +    0] = k0;   keybuf[base +  256] = k1;
        keybuf[base +  512] = k2;   keybuf[base +  768] = k3;
        keybuf[base + 2048] = k4;   keybuf[base + 2304] = k5;
        keybuf[base + 2560] = k6;   keybuf[base + 2816] = k7;
        keybuf[base + 4096] = k8;   keybuf[base + 4352] = k9;
        keybuf[base + 4608] = k10;  keybuf[base + 4864] = k11;
        keybuf[base + 6144] = k12;  keybuf[base + 6400] = k13;
        keybuf[base + 6656] = k14;  keybuf[base + 6912] = k15;
    }
    __syncthreads();

    // merge: wave wv owns rows wv*4+g (g=lane>>4); 16 lanes scan 256 bins.
    {
        const int g = lane >> 4, li = lane & 15;
        const int row = wv * 4 + g;
        uint32_t K0 = ~0u, K1 = ~0u, K2 = ~0u;
#pragma unroll
        for (int s = 0; s < 16; ++s) ins3(keybuf[row * 256 + li + s * 16], K0, K1, K2);
#pragma unroll
        for (int mk = 1; mk < 16; mk <<= 1) {
            uint32_t r0 = (uint32_t)__shfl_xor((int)K0, mk);
            uint32_t r1 = (uint32_t)__shfl_xor((int)K1, mk);
            uint32_t r2 = (uint32_t)__shfl_xor((int)K2, mk);
            ins3(r0, K0, K1, K2);
            ins3(r1, K0, K1, K2);
            ins3(r2, K0, K1, K2);
        }
        if (li == 0) {
            top3j[row * 3 + 0] = (int)(K0 & 8191u);
            top3j[row * 3 + 1] = (int)(K1 & 8191u);
            top3j[row * 3 + 2] = (int)(K2 & 8191u);
        }
    }
    __syncthreads();

    // gather: wave wv handles queries wv*4 .. wv*4+3
    float acc = 0.0f;
    const size_t abase = (size_t)bb * NPTS;
    for (int i = 0; i < 4; ++i) {
        const int q = wv * 4 + i;
        const int j0 = top3j[q * 3 + 0];
        const int j1 = top3j[q * 3 + 1];
        const int j2 = top3j[q * 3 + 2];
        const int qi = qbase + q;
        const float xp = xb[qi * 3 + 0], yp = xb[qi * 3 + 1], zp = xb[qi * 3 + 2];
        acc += point_contrib(j0, j1, j2, lane, xp, yp, zp,
                             xb, rot, sc, colr, opac, abase, inv_nb);
    }

#pragma unroll
    for (int off = 32; off > 0; off >>= 1) acc += __shfl_xor(acc, off);
    if (lane == 0) atomicAdd(&blockAcc, acc);
    __syncthreads();
    if (tid == 0) atomicAdd(out, blockAcc);
}

extern "C" void kernel_launch(void* const* d_in, const int* in_sizes, int n_in,
                              void* d_out, int out_size, void* d_ws, size_t ws_size,
                              hipStream_t stream) {
    const float* xyz  = (const float*)d_in[0];
    const float* rot  = (const float*)d_in[1];
    const float* sc   = (const float*)d_in[2];
    const float* colr = (const float*)d_in[3];
    const float* opac = (const float*)d_in[4];
    float* out = (float*)d_out;

    const int B = in_sizes[0] / (NPTS * 3);  // = 2
    const float inv_nb = 1.0f / ((float)NPTS * (float)B);
    const int total = B * NPTS;

    // pack_kernel also zeroes d_out (stream-ordered before the main kernel);
    // d_ws is fully rewritten each launch (re-poison safe).
    pack_kernel<<<dim3((total + 255) / 256), dim3(256), 0, stream>>>(
        xyz, (uint4*)d_ws, out, total);
    knn_mfma_kernel<<<dim3(B * BLKS_PER_BATCH), dim3(BLK), 0, stream>>>(
        xyz, rot, sc, colr, opac, (const uint4*)d_ws, out, inv_nb);
}